// Round 10
// baseline (63.739 us; speedup 1.0000x reference)
//
#include <hip/hip_runtime.h>

// SpatialEmbedding via hybrid histogram + cos/sin table + f16 MFMA GEMM.
// out[bi][2m]   = sum_j amp_ij * cos(k_m r_ij)
// out[bi][2m+1] = sum_j amp_ij * sin(k_m r_ij),  amp = 1/(4*pi*r)
// Pipeline: bin (u32 fixed-point LDS histogram over r, at the ds-atomic
// 1-lane/cy/CU floor) + table (fused, block-role branch) -> W[8192][1024] f16,
// T[512][1024] f16; out = W * T^T via MFMA GEMM.
// R10 GEMM: PURE-REGISTER, NO LDS. Each block reads its panels exactly once
// (reuse lives in registers), so R9's LDS staging was pure overhead — the
// direct fragment gather (16 rows x 64B contiguous segments per instr) is
// L2-friendly. Double-buffered frags via 2x unroll; no barriers, no asm.

constexpr int N_TOK   = 2048;
constexpr int DMODEL  = 512;
constexpr int Q_BINS  = 1024;
constexpr float R_MAX     = 96.0f;              // max pair distance ~90 A
constexpr float DELTA     = R_MAX / Q_BINS;     // 0.09375 (exact)
constexpr float INV_DELTA = Q_BINS / R_MAX;     // 10.667
constexpr float RC_SQ     = 36.0f;              // lerp below r=6 A (~2% of pairs)
constexpr float FXP_SCALE     = 16777216.0f;    // 2^24
constexpr float FXP_INV_SCALE = 1.0f / FXP_SCALE;

#define LOG2_50_OVER_255 0.0221327692901077f
#define INV_FOUR_PI      0.07957747154594767f

typedef _Float16 f16x8 __attribute__((ext_vector_type(8)));
typedef _Float16 f16x4 __attribute__((ext_vector_type(4)));
typedef float    f32x4 __attribute__((ext_vector_type(4)));

// ---------------------------------------------------------------- kernel 1
// Fused bin + table. Blocks [0,8192): per-row histogram W[bi][q] = sum_j amp
// (hybrid deposit, u32 fixed-point ds_add_u32). Blocks [8192,8704): table
// T[c][q] = cis(2*pi*q*DELTA/lam_m), c = 2m + (0=cos,1=sin), [512][1024] f16.
__global__ __launch_bounds__(256)
void bin_table_kernel(const float* __restrict__ coords,
                      const unsigned char* __restrict__ mask,
                      _Float16* __restrict__ Wg,
                      _Float16* __restrict__ Tg)
{
    const int tid = threadIdx.x;

    if (blockIdx.x >= 8192) {
        // ---- table role
        const int c = blockIdx.x - 8192;       // 0..511
        const int m = c >> 1;
        const float inv_lam = 0.5f * exp2f(-(float)m * LOG2_50_OVER_255);
        const int q0 = tid * 4;
        f16x4 v;
        #pragma unroll
        for (int u = 0; u < 4; ++u) {
            float t = ((float)(q0 + u) * DELTA) * inv_lam;  // revolutions
            t -= floorf(t);
            float val = (c & 1) ? __builtin_amdgcn_sinf(t)
                                : __builtin_amdgcn_cosf(t);
            v[u] = (_Float16)val;
        }
        *reinterpret_cast<f16x4*>(&Tg[(size_t)c * Q_BINS + q0]) = v;
        return;
    }

    // ---- bin role
    const int bi = blockIdx.x;
    const int b  = bi >> 11;
    const int i  = bi & (N_TOK - 1);

    __shared__ unsigned int W[Q_BINS];     // 4 KB u32 fixed-point accumulation
    for (int q = tid; q < Q_BINS; q += 256) W[q] = 0u;
    __syncthreads();

    const unsigned char* mrow = mask + (size_t)b * N_TOK;
    const bool row_valid = (mrow[i] == 0);

    if (row_valid) {
        const float xi = coords[(size_t)bi * 3 + 0];
        const float yi = coords[(size_t)bi * 3 + 1];
        const float zi = coords[(size_t)bi * 3 + 2];
        #pragma unroll
        for (int jj = 0; jj < N_TOK / 256; ++jj) {
            const int j = tid + jj * 256;
            if (j == i || mrow[j] != 0) continue;
            const float* cj = coords + ((size_t)b * N_TOK + j) * 3;
            float dx = xi - cj[0];
            float dy = yi - cj[1];
            float dz = zi - cj[2];
            float sq = fmaf(dx, dx, fmaf(dy, dy, dz * dz));
            float inv_r = rsqrtf(sq);
            float r     = sq * inv_r;
            float amp   = inv_r * INV_FOUR_PI;
            float u     = r * INV_DELTA;
            if (sq < RC_SQ) {
                // close pair: linear interp (second-order error; amp ~ 1/r
                // makes close pairs dominate first-order error)
                float qf = floorf(u);
                int   q  = (int)qf;
                float w  = u - qf;
                atomicAdd(&W[q],     (unsigned int)(amp * (1.0f - w) * FXP_SCALE));
                atomicAdd(&W[q + 1], (unsigned int)(amp * w * FXP_SCALE));
            } else {
                // far pair: nearest bin (amp <= 0.0133; incoherent ~0.03 max)
                int q = (int)(u + 0.5f);
                if (q > Q_BINS - 1) q = Q_BINS - 1; // safety clamp
                atomicAdd(&W[q], (unsigned int)(amp * FXP_SCALE));
            }
        }
    }
    __syncthreads();

    _Float16* wrow = Wg + (size_t)bi * Q_BINS;
    const int q0 = tid * 4;
    f16x4 v;
    #pragma unroll
    for (int u = 0; u < 4; ++u)
        v[u] = (_Float16)((float)W[q0 + u] * FXP_INV_SCALE);
    *reinterpret_cast<f16x4*>(&wrow[q0]) = v;
}

// ---------------------------------------------------------------- kernel 2
// C(8192x512 f32) = W(8192x1024 f16) * T^T  (T stored as [512][1024]).
// PURE-REGISTER: 1024 blocks x 64 threads; each wave owns one 64x64 output
// tile (acc 4x4 of 16x16x32). Fragments loaded directly from global (L2):
// per instr a quarter-wave (fr=0..15) reads 16 rows, fq picks one of four
// contiguous 16B chunks -> 16 x 64B segments. Frags double-buffered in regs
// via 2x unroll; compiler manages all waitcnts. No LDS, no barriers, no asm.
// bx-fast bid mapping keeps A-panel sharers (by=0..7, bids +128k) co-XCD.
__global__ __launch_bounds__(64)
void gemm_kernel(const _Float16* __restrict__ Wg,
                 const _Float16* __restrict__ Tg,
                 float* __restrict__ out)
{
    constexpr int NT = Q_BINS / 64;         // 16 K-steps
    const int bid  = blockIdx.x;
    const int bx   = bid & 127;             // M-tile 0..127
    const int by   = bid >> 7;              // N-tile 0..7
    const int lane = threadIdx.x;           // one wave

    const int fr = lane & 15;               // fragment row
    const int fq = lane >> 4;               // k-quad 0..3 (8 f16 each)

    // lane-fixed bases; frag (x, kk) at step t lives at +x*16*Q_BINS + t*64 + kk*32
    const _Float16* Abase = Wg + (size_t)(bx * 64 + fr) * Q_BINS + fq * 8;
    const _Float16* Bbase = Tg + (size_t)(by * 64 + fr) * Q_BINS + fq * 8;

    f32x4 acc[4][4] = {};
    f16x8 aE[4][2], bE[4][2], aO[4][2], bO[4][2];

    auto load = [&](f16x8 (&a)[4][2], f16x8 (&b)[4][2], int t) {
        #pragma unroll
        for (int x = 0; x < 4; ++x)
            #pragma unroll
            for (int kk = 0; kk < 2; ++kk) {
                a[x][kk] = *reinterpret_cast<const f16x8*>(
                    Abase + (size_t)x * 16 * Q_BINS + t * 64 + kk * 32);
                b[x][kk] = *reinterpret_cast<const f16x8*>(
                    Bbase + (size_t)x * 16 * Q_BINS + t * 64 + kk * 32);
            }
    };
    auto compute = [&](f16x8 (&a)[4][2], f16x8 (&b)[4][2]) {
        #pragma unroll
        for (int kk = 0; kk < 2; ++kk)
            #pragma unroll
            for (int m = 0; m < 4; ++m)
                #pragma unroll
                for (int n = 0; n < 4; ++n)
                    acc[m][n] = __builtin_amdgcn_mfma_f32_16x16x32_f16(
                        a[m][kk], b[n][kk], acc[m][n], 0, 0, 0);
    };

    load(aE, bE, 0);
    for (int t = 0; t < NT; t += 2) {       // NT even
        load(aO, bO, t + 1);                // prefetch odd step
        compute(aE, bE);
        if (t + 2 < NT) load(aE, bE, t + 2);// prefetch next even step
        compute(aO, bO);
    }

    // epilogue: C/D layout col = lane&15, row = (lane>>4)*4 + reg
    const int crow = fq * 4;
    #pragma unroll
    for (int m = 0; m < 4; ++m)
        #pragma unroll
        for (int n = 0; n < 4; ++n)
            #pragma unroll
            for (int r = 0; r < 4; ++r) {
                int grow = bx * 64 + m * 16 + crow + r;
                int gcol = by * 64 + n * 16 + fr;
                out[(size_t)grow * DMODEL + gcol] = acc[m][n][r];
            }
}

// ---------------------------------------------------------------- fallback
// (direct evaluation, used only if the workspace is too small)
__global__ __launch_bounds__(256)
void spatial_embed_fallback(const float* __restrict__ coords,
                            const unsigned char* __restrict__ mask,
                            float* __restrict__ out)
{
    const int bi  = blockIdx.x;
    const int b   = bi >> 11;
    const int i   = bi & (N_TOK - 1);
    const int tid = threadIdx.x;

    __shared__ float2 ra[N_TOK];
    const float xi = coords[(size_t)bi * 3 + 0];
    const float yi = coords[(size_t)bi * 3 + 1];
    const float zi = coords[(size_t)bi * 3 + 2];
    const unsigned char* mrow = mask + (size_t)b * N_TOK;

    for (int j = tid; j < N_TOK; j += 256) {
        const float* cj = coords + ((size_t)b * N_TOK + j) * 3;
        float dx = xi - cj[0], dy = yi - cj[1], dz = zi - cj[2];
        float sq = fmaf(dx, dx, fmaf(dy, dy, dz * dz));
        bool pv = (j != i) && (mrow[j] == 0);
        sq = pv ? sq : 1.0f;
        float inv_r = rsqrtf(sq);
        ra[j] = make_float2(sq * inv_r, pv ? inv_r * INV_FOUR_PI : 0.0f);
    }
    __syncthreads();

    const float inv_lam = 0.5f * exp2f(-(float)tid * LOG2_50_OVER_255);
    float re = 0.0f, im = 0.0f;
    #pragma unroll 8
    for (int j = 0; j < N_TOK; ++j) {
        float2 v = ra[j];
        float t  = v.x * inv_lam;
        t -= floorf(t);
        re = fmaf(v.y, __builtin_amdgcn_cosf(t), re);
        im = fmaf(v.y, __builtin_amdgcn_sinf(t), im);
    }
    const float vi = (mrow[i] == 0) ? 1.0f : 0.0f;
    reinterpret_cast<float2*>(out)[(size_t)bi * 256 + tid] =
        make_float2(re * vi, im * vi);
}

extern "C" void kernel_launch(void* const* d_in, const int* in_sizes, int n_in,
                              void* d_out, int out_size, void* d_ws, size_t ws_size,
                              hipStream_t stream)
{
    const float* coords       = (const float*)d_in[0];
    const unsigned char* mask = (const unsigned char*)d_in[1];
    float* out                = (float*)d_out;
    const int BN = in_sizes[1];                       // B * N = 8192

    const size_t W_BYTES = (size_t)8192 * Q_BINS * sizeof(_Float16);   // 16 MB
    const size_t T_BYTES = (size_t)DMODEL * Q_BINS * sizeof(_Float16); //  1 MB

    if (BN == 8192 && ws_size >= W_BYTES + T_BYTES) {
        _Float16* Wg = (_Float16*)d_ws;
        _Float16* Tg = (_Float16*)((char*)d_ws + W_BYTES);
        bin_table_kernel<<<8192 + DMODEL, 256, 0, stream>>>(coords, mask, Wg, Tg);
        gemm_kernel<<<1024, 64, 0, stream>>>(Wg, Tg, out);
    } else {
        spatial_embed_fallback<<<BN, 256, 0, stream>>>(coords, mask, out);
    }
}

// Round 11
// 51.236 us; speedup vs baseline: 1.2440x; 1.2440x over previous
//
#include <hip/hip_runtime.h>

// SpatialEmbedding via hybrid histogram + cos/sin table + f16 MFMA GEMM.
// out[bi][2m]   = sum_j amp_ij * cos(k_m r_ij)
// out[bi][2m+1] = sum_j amp_ij * sin(k_m r_ij),  amp = 1/(4*pi*r)
// Pipeline: fused bin+table kernel -> W[8192][1024] f16, T[512][1024] f16;
// then out = W * T^T via MFMA GEMM.
// R11: revert gemm to R9's wave-private LDS pipeline (R10 post-mortem: the
// pure-register gather quadrupled L2 request count — 16 scattered 64B
// segments/instr vs staging's 8x128B; LDS staging is the coalescing
// reshaper, not a reuse cache). Keep R10's fused bin+table and RC_SQ=36.
// Add s_setprio around the MFMA cluster (T5: independent 1-wave blocks at
// different phases = the regime where setprio measured +4-7%).

constexpr int N_TOK   = 2048;
constexpr int DMODEL  = 512;
constexpr int Q_BINS  = 1024;
constexpr float R_MAX     = 96.0f;              // max pair distance ~90 A
constexpr float DELTA     = R_MAX / Q_BINS;     // 0.09375 (exact)
constexpr float INV_DELTA = Q_BINS / R_MAX;     // 10.667
constexpr float RC_SQ     = 36.0f;              // lerp below r=6 A (~2% of pairs)
constexpr float FXP_SCALE     = 16777216.0f;    // 2^24
constexpr float FXP_INV_SCALE = 1.0f / FXP_SCALE;

#define LOG2_50_OVER_255 0.0221327692901077f
#define INV_FOUR_PI      0.07957747154594767f

typedef _Float16 f16x8 __attribute__((ext_vector_type(8)));
typedef _Float16 f16x4 __attribute__((ext_vector_type(4)));
typedef float    f32x4 __attribute__((ext_vector_type(4)));

typedef const __attribute__((address_space(1))) unsigned int* gas_t;
typedef __attribute__((address_space(3))) unsigned int* las_t;

// ---------------------------------------------------------------- kernel 1
// Fused bin + table. Blocks [0,8192): per-row histogram W[bi][q] = sum_j amp
// (hybrid deposit, u32 fixed-point ds_add_u32 — native RMW path, at the
// ~1 lane-op/cy/CU ds-atomic floor). Blocks [8192,8704): table
// T[c][q] = cis(2*pi*q*DELTA/lam_m), c = 2m + (0=cos,1=sin), [512][1024] f16.
__global__ __launch_bounds__(256)
void bin_table_kernel(const float* __restrict__ coords,
                      const unsigned char* __restrict__ mask,
                      _Float16* __restrict__ Wg,
                      _Float16* __restrict__ Tg)
{
    const int tid = threadIdx.x;

    if (blockIdx.x >= 8192) {
        // ---- table role
        const int c = blockIdx.x - 8192;       // 0..511
        const int m = c >> 1;
        const float inv_lam = 0.5f * exp2f(-(float)m * LOG2_50_OVER_255);
        const int q0 = tid * 4;
        f16x4 v;
        #pragma unroll
        for (int u = 0; u < 4; ++u) {
            float t = ((float)(q0 + u) * DELTA) * inv_lam;  // revolutions
            t -= floorf(t);
            float val = (c & 1) ? __builtin_amdgcn_sinf(t)
                                : __builtin_amdgcn_cosf(t);
            v[u] = (_Float16)val;
        }
        *reinterpret_cast<f16x4*>(&Tg[(size_t)c * Q_BINS + q0]) = v;
        return;
    }

    // ---- bin role
    const int bi = blockIdx.x;
    const int b  = bi >> 11;
    const int i  = bi & (N_TOK - 1);

    __shared__ unsigned int W[Q_BINS];     // 4 KB u32 fixed-point accumulation
    for (int q = tid; q < Q_BINS; q += 256) W[q] = 0u;
    __syncthreads();

    const unsigned char* mrow = mask + (size_t)b * N_TOK;
    const bool row_valid = (mrow[i] == 0);

    if (row_valid) {
        const float xi = coords[(size_t)bi * 3 + 0];
        const float yi = coords[(size_t)bi * 3 + 1];
        const float zi = coords[(size_t)bi * 3 + 2];
        #pragma unroll
        for (int jj = 0; jj < N_TOK / 256; ++jj) {
            const int j = tid + jj * 256;
            if (j == i || mrow[j] != 0) continue;
            const float* cj = coords + ((size_t)b * N_TOK + j) * 3;
            float dx = xi - cj[0];
            float dy = yi - cj[1];
            float dz = zi - cj[2];
            float sq = fmaf(dx, dx, fmaf(dy, dy, dz * dz));
            float inv_r = rsqrtf(sq);
            float r     = sq * inv_r;
            float amp   = inv_r * INV_FOUR_PI;
            float u     = r * INV_DELTA;
            if (sq < RC_SQ) {
                // close pair: linear interp (second-order error; amp ~ 1/r
                // makes close pairs dominate first-order error)
                float qf = floorf(u);
                int   q  = (int)qf;
                float w  = u - qf;
                atomicAdd(&W[q],     (unsigned int)(amp * (1.0f - w) * FXP_SCALE));
                atomicAdd(&W[q + 1], (unsigned int)(amp * w * FXP_SCALE));
            } else {
                // far pair: nearest bin (amp <= 0.0133; incoherent ~0.03 max)
                int q = (int)(u + 0.5f);
                if (q > Q_BINS - 1) q = Q_BINS - 1; // safety clamp
                atomicAdd(&W[q], (unsigned int)(amp * FXP_SCALE));
            }
        }
    }
    __syncthreads();

    _Float16* wrow = Wg + (size_t)bi * Q_BINS;
    const int q0 = tid * 4;
    f16x4 v;
    #pragma unroll
    for (int u = 0; u < 4; ++u)
        v[u] = (_Float16)((float)W[q0 + u] * FXP_INV_SCALE);
    *reinterpret_cast<f16x4*>(&wrow[q0]) = v;
}

// ---------------------------------------------------------------- kernel 2
// C(8192x512 f32) = W(8192x1024 f16) * T^T  (T stored as [512][1024]).
// WAVE-PRIVATE: 1024 blocks x 64 threads; each wave owns one 64x64 output
// tile (acc 4x4 of 16x16x32) and a private double-buffered LDS set
// (A 8KB + B 8KB per buffer = 32 KB/block; 4 blocks/CU = 128 KB).
// K-loop sync = per-wave counted vmcnt(16) only; NO barriers. LDS staging is
// the coalescing reshaper: gload_lds reads 8x128B segments/instr vs the
// direct-gather's 16x64B (R10 regression).
// XOR-swizzle both sides (rule #21): phys 16B-chunk kcp at (row,kcp) holds
// logical kc = kcp^(row&7); source pre-swizzled, ds_read applies same XOR.
__global__ __launch_bounds__(64)
void gemm_kernel(const _Float16* __restrict__ Wg,
                 const _Float16* __restrict__ Tg,
                 float* __restrict__ out)
{
    constexpr int NT = Q_BINS / 64;         // 16 K-steps
    __shared__ _Float16 Ash[2][64 * 64];    // 8 KB per buffer
    __shared__ _Float16 Bsh[2][64 * 64];    // 32 KB total per block

    const int bid  = blockIdx.x;
    const int bx   = bid & 127;             // M-tile 0..127 (A-sharers co-XCD:
    const int by   = bid >> 7;              //   bids differ by 128 = 0 mod 8)
    const int lane = threadIdx.x;           // one wave

    const int fr = lane & 15;               // fragment row/col
    const int fq = lane >> 4;               // k-quad 0..3 (8 f16 each)

    const _Float16* Abase = Wg + (size_t)bx * 64 * Q_BINS;
    const _Float16* Bbase = Tg + (size_t)by * 64 * Q_BINS;

    // stage one 64x64 f16 tile pair: 512+512 16B chunks, 8+8 per lane.
    auto stage = [&](int buf, int t) {
        const int kt = t * 64;
        #pragma unroll
        for (int r = 0; r < 8; ++r) {
            int chunk = r * 64 + lane;
            int row = chunk >> 3, kcp = chunk & 7;
            int kcl = kcp ^ (row & 7);      // pre-swizzled source chunk
            __builtin_amdgcn_global_load_lds(
                (gas_t)(const void*)(Abase + (size_t)row * Q_BINS + kt + kcl * 8),
                (las_t)(void*)&Ash[buf][chunk * 8], 16, 0, 0);
        }
        #pragma unroll
        for (int r = 0; r < 8; ++r) {
            int chunk = r * 64 + lane;
            int row = chunk >> 3, kcp = chunk & 7;
            int kcl = kcp ^ (row & 7);
            __builtin_amdgcn_global_load_lds(
                (gas_t)(const void*)(Bbase + (size_t)row * Q_BINS + kt + kcl * 8),
                (las_t)(void*)&Bsh[buf][chunk * 8], 16, 0, 0);
        }
    };

    f32x4 acc[4][4] = {};

    stage(0, 0);                            // 16 loads in flight
    int cur = 0;
    for (int t = 0; t < NT; ++t) {
        if (t + 1 < NT) {
            stage(cur ^ 1, t + 1);          // 16 newest loads (next tile)
            // wait for buf[cur]'s 16 (issued one full iteration ago);
            // next tile's 16 stay in flight across the compute phase.
            asm volatile("s_waitcnt vmcnt(16)" ::: "memory");
        } else {
            asm volatile("s_waitcnt vmcnt(0)" ::: "memory");
        }

        f16x8 a[4][2], b[4][2];
        #pragma unroll
        for (int m = 0; m < 4; ++m) {
            int row = m * 16 + fr;
            #pragma unroll
            for (int kk = 0; kk < 2; ++kk) {
                int kcp = (kk * 4 + fq) ^ (fr & 7);      // swizzled read
                a[m][kk] = *reinterpret_cast<const f16x8*>(
                    &Ash[cur][row * 64 + kcp * 8]);
            }
        }
        #pragma unroll
        for (int n = 0; n < 4; ++n) {
            int row = n * 16 + fr;
            #pragma unroll
            for (int kk = 0; kk < 2; ++kk) {
                int kcp = (kk * 4 + fq) ^ (fr & 7);
                b[n][kk] = *reinterpret_cast<const f16x8*>(
                    &Bsh[cur][row * 64 + kcp * 8]);
            }
        }

        __builtin_amdgcn_s_setprio(1);      // T5: favor the MFMA cluster
        #pragma unroll
        for (int kk = 0; kk < 2; ++kk)
            #pragma unroll
            for (int m = 0; m < 4; ++m)
                #pragma unroll
                for (int n = 0; n < 4; ++n)
                    acc[m][n] = __builtin_amdgcn_mfma_f32_16x16x32_f16(
                        a[m][kk], b[n][kk], acc[m][n], 0, 0, 0);
        __builtin_amdgcn_s_setprio(0);

        cur ^= 1;
    }

    // epilogue: C/D layout col = lane&15, row = (lane>>4)*4 + reg
    const int crow = fq * 4;
    #pragma unroll
    for (int m = 0; m < 4; ++m)
        #pragma unroll
        for (int n = 0; n < 4; ++n)
            #pragma unroll
            for (int r = 0; r < 4; ++r) {
                int grow = bx * 64 + m * 16 + crow + r;
                int gcol = by * 64 + n * 16 + fr;
                out[(size_t)grow * DMODEL + gcol] = acc[m][n][r];
            }
}

// ---------------------------------------------------------------- fallback
// (direct evaluation, used only if the workspace is too small)
__global__ __launch_bounds__(256)
void spatial_embed_fallback(const float* __restrict__ coords,
                            const unsigned char* __restrict__ mask,
                            float* __restrict__ out)
{
    const int bi  = blockIdx.x;
    const int b   = bi >> 11;
    const int i   = bi & (N_TOK - 1);
    const int tid = threadIdx.x;

    __shared__ float2 ra[N_TOK];
    const float xi = coords[(size_t)bi * 3 + 0];
    const float yi = coords[(size_t)bi * 3 + 1];
    const float zi = coords[(size_t)bi * 3 + 2];
    const unsigned char* mrow = mask + (size_t)b * N_TOK;

    for (int j = tid; j < N_TOK; j += 256) {
        const float* cj = coords + ((size_t)b * N_TOK + j) * 3;
        float dx = xi - cj[0], dy = yi - cj[1], dz = zi - cj[2];
        float sq = fmaf(dx, dx, fmaf(dy, dy, dz * dz));
        bool pv = (j != i) && (mrow[j] == 0);
        sq = pv ? sq : 1.0f;
        float inv_r = rsqrtf(sq);
        ra[j] = make_float2(sq * inv_r, pv ? inv_r * INV_FOUR_PI : 0.0f);
    }
    __syncthreads();

    const float inv_lam = 0.5f * exp2f(-(float)tid * LOG2_50_OVER_255);
    float re = 0.0f, im = 0.0f;
    #pragma unroll 8
    for (int j = 0; j < N_TOK; ++j) {
        float2 v = ra[j];
        float t  = v.x * inv_lam;
        t -= floorf(t);
        re = fmaf(v.y, __builtin_amdgcn_cosf(t), re);
        im = fmaf(v.y, __builtin_amdgcn_sinf(t), im);
    }
    const float vi = (mrow[i] == 0) ? 1.0f : 0.0f;
    reinterpret_cast<float2*>(out)[(size_t)bi * 256 + tid] =
        make_float2(re * vi, im * vi);
}

extern "C" void kernel_launch(void* const* d_in, const int* in_sizes, int n_in,
                              void* d_out, int out_size, void* d_ws, size_t ws_size,
                              hipStream_t stream)
{
    const float* coords       = (const float*)d_in[0];
    const unsigned char* mask = (const unsigned char*)d_in[1];
    float* out                = (float*)d_out;
    const int BN = in_sizes[1];                       // B * N = 8192

    const size_t W_BYTES = (size_t)8192 * Q_BINS * sizeof(_Float16);   // 16 MB
    const size_t T_BYTES = (size_t)DMODEL * Q_BINS * sizeof(_Float16); //  1 MB

    if (BN == 8192 && ws_size >= W_BYTES + T_BYTES) {
        _Float16* Wg = (_Float16*)d_ws;
        _Float16* Tg = (_Float16*)((char*)d_ws + W_BYTES);
        bin_table_kernel<<<8192 + DMODEL, 256, 0, stream>>>(coords, mask, Wg, Tg);
        gemm_kernel<<<1024, 64, 0, stream>>>(Wg, Tg, out);
    } else {
        spatial_embed_fallback<<<BN, 256, 0, stream>>>(coords, mask, out);
    }
}

// Round 12
// 44.434 us; speedup vs baseline: 1.4345x; 1.1531x over previous
//
#include <hip/hip_runtime.h>

// SpatialEmbedding via hybrid histogram + cos/sin table + f16 MFMA GEMM.
// out[bi][2m]   = sum_j amp_ij * cos(k_m r_ij)
// out[bi][2m+1] = sum_j amp_ij * sin(k_m r_ij),  amp = 1/(4*pi*r)
// Pipeline: fused bin+table kernel -> W[8192][768] f16, T[512][768] f16;
// then out = W * T^T via MFMA GEMM (wave-private, barrier-free).
// R12: Q_BINS 1024 -> 768 (DELTA=0.125 exact): -25% gemm steps/LDS/W bytes,
// bin unchanged (ds-atomic-bound). Error: nearest-bin incoherent sigma ~
// 0.023 -> max ~0.10 < 0.199 threshold; close pairs (r<6) remain lerp'd.

constexpr int N_TOK   = 2048;
constexpr int DMODEL  = 512;
constexpr int Q_BINS  = 768;
constexpr float R_MAX     = 96.0f;              // max pair distance ~90 A
constexpr float DELTA     = R_MAX / Q_BINS;     // 0.125 (exact)
constexpr float INV_DELTA = Q_BINS / R_MAX;     // 8 (exact)
constexpr float RC_SQ     = 36.0f;              // lerp below r=6 A (~2% of pairs)
constexpr float FXP_SCALE     = 16777216.0f;    // 2^24
constexpr float FXP_INV_SCALE = 1.0f / FXP_SCALE;

#define LOG2_50_OVER_255 0.0221327692901077f
#define INV_FOUR_PI      0.07957747154594767f

typedef _Float16 f16x8 __attribute__((ext_vector_type(8)));
typedef _Float16 f16x4 __attribute__((ext_vector_type(4)));
typedef float    f32x4 __attribute__((ext_vector_type(4)));

typedef const __attribute__((address_space(1))) unsigned int* gas_t;
typedef __attribute__((address_space(3))) unsigned int* las_t;

// ---------------------------------------------------------------- kernel 1
// Fused bin + table. Blocks [0,8192): per-row histogram W[bi][q] = sum_j amp
// (hybrid deposit, u32 fixed-point ds_add_u32 — native RMW path, at the
// ~1 lane-op/cy/CU ds-atomic floor). Blocks [8192,8704): table
// T[c][q] = cis(2*pi*q*DELTA/lam_m), c = 2m + (0=cos,1=sin), [512][768] f16.
__global__ __launch_bounds__(256)
void bin_table_kernel(const float* __restrict__ coords,
                      const unsigned char* __restrict__ mask,
                      _Float16* __restrict__ Wg,
                      _Float16* __restrict__ Tg)
{
    const int tid = threadIdx.x;

    if (blockIdx.x >= 8192) {
        // ---- table role (192 threads x f16x4 = 768 bins)
        const int c = blockIdx.x - 8192;       // 0..511
        const int m = c >> 1;
        const float inv_lam = 0.5f * exp2f(-(float)m * LOG2_50_OVER_255);
        if (tid < 192) {
            const int q0 = tid * 4;
            f16x4 v;
            #pragma unroll
            for (int u = 0; u < 4; ++u) {
                float t = ((float)(q0 + u) * DELTA) * inv_lam;  // revolutions
                t -= floorf(t);
                float val = (c & 1) ? __builtin_amdgcn_sinf(t)
                                    : __builtin_amdgcn_cosf(t);
                v[u] = (_Float16)val;
            }
            *reinterpret_cast<f16x4*>(&Tg[(size_t)c * Q_BINS + q0]) = v;
        }
        return;
    }

    // ---- bin role
    const int bi = blockIdx.x;
    const int b  = bi >> 11;
    const int i  = bi & (N_TOK - 1);

    __shared__ unsigned int W[Q_BINS];     // 3 KB u32 fixed-point accumulation
    for (int q = tid; q < Q_BINS; q += 256) W[q] = 0u;
    __syncthreads();

    const unsigned char* mrow = mask + (size_t)b * N_TOK;
    const bool row_valid = (mrow[i] == 0);

    if (row_valid) {
        const float xi = coords[(size_t)bi * 3 + 0];
        const float yi = coords[(size_t)bi * 3 + 1];
        const float zi = coords[(size_t)bi * 3 + 2];
        #pragma unroll
        for (int jj = 0; jj < N_TOK / 256; ++jj) {
            const int j = tid + jj * 256;
            if (j == i || mrow[j] != 0) continue;
            const float* cj = coords + ((size_t)b * N_TOK + j) * 3;
            float dx = xi - cj[0];
            float dy = yi - cj[1];
            float dz = zi - cj[2];
            float sq = fmaf(dx, dx, fmaf(dy, dy, dz * dz));
            float inv_r = rsqrtf(sq);
            float r     = sq * inv_r;
            float amp   = inv_r * INV_FOUR_PI;
            float u     = r * INV_DELTA;
            if (sq < RC_SQ) {
                // close pair: linear interp (second-order error; amp ~ 1/r
                // makes close pairs dominate first-order error). u < 48.
                float qf = floorf(u);
                int   q  = (int)qf;
                float w  = u - qf;
                atomicAdd(&W[q],     (unsigned int)(amp * (1.0f - w) * FXP_SCALE));
                atomicAdd(&W[q + 1], (unsigned int)(amp * w * FXP_SCALE));
            } else {
                // far pair: nearest bin (amp <= 0.0133; incoherent max ~0.10)
                int q = (int)(u + 0.5f);
                if (q > Q_BINS - 1) q = Q_BINS - 1; // safety clamp
                atomicAdd(&W[q], (unsigned int)(amp * FXP_SCALE));
            }
        }
    }
    __syncthreads();

    // export 768 bins: 192 threads x f16x4
    if (tid < 192) {
        _Float16* wrow = Wg + (size_t)bi * Q_BINS;
        const int q0 = tid * 4;
        f16x4 v;
        #pragma unroll
        for (int u = 0; u < 4; ++u)
            v[u] = (_Float16)((float)W[q0 + u] * FXP_INV_SCALE);
        *reinterpret_cast<f16x4*>(&wrow[q0]) = v;
    }
}

// ---------------------------------------------------------------- kernel 2
// C(8192x512 f32) = W(8192x768 f16) * T^T  (T stored as [512][768]).
// WAVE-PRIVATE: 1024 blocks x 64 threads; each wave owns one 64x64 output
// tile (acc 4x4 of 16x16x32) and a private double-buffered LDS set
// (A 8KB + B 8KB per buffer = 32 KB/block; 4 blocks/CU = 128 KB, exact fit).
// K-loop sync = per-wave counted vmcnt(16) only; NO barriers. LDS staging is
// the coalescing reshaper: gload_lds reads 8x128B segments/instr vs the
// direct-gather's 16x64B (R10 regression).
// XOR-swizzle both sides (rule #21): phys 16B-chunk kcp at (row,kcp) holds
// logical kc = kcp^(row&7); source pre-swizzled, ds_read applies same XOR.
__global__ __launch_bounds__(64)
void gemm_kernel(const _Float16* __restrict__ Wg,
                 const _Float16* __restrict__ Tg,
                 float* __restrict__ out)
{
    constexpr int NT = Q_BINS / 64;         // 12 K-steps
    __shared__ _Float16 Ash[2][64 * 64];    // 8 KB per buffer
    __shared__ _Float16 Bsh[2][64 * 64];    // 32 KB total per block

    const int bid  = blockIdx.x;
    const int bx   = bid & 127;             // M-tile 0..127 (A-sharers co-XCD:
    const int by   = bid >> 7;              //   bids differ by 128 = 0 mod 8)
    const int lane = threadIdx.x;           // one wave

    const int fr = lane & 15;               // fragment row/col
    const int fq = lane >> 4;               // k-quad 0..3 (8 f16 each)

    const _Float16* Abase = Wg + (size_t)bx * 64 * Q_BINS;
    const _Float16* Bbase = Tg + (size_t)by * 64 * Q_BINS;

    // stage one 64x64 f16 tile pair: 512+512 16B chunks, 8+8 per lane.
    auto stage = [&](int buf, int t) {
        const int kt = t * 64;
        #pragma unroll
        for (int r = 0; r < 8; ++r) {
            int chunk = r * 64 + lane;
            int row = chunk >> 3, kcp = chunk & 7;
            int kcl = kcp ^ (row & 7);      // pre-swizzled source chunk
            __builtin_amdgcn_global_load_lds(
                (gas_t)(const void*)(Abase + (size_t)row * Q_BINS + kt + kcl * 8),
                (las_t)(void*)&Ash[buf][chunk * 8], 16, 0, 0);
        }
        #pragma unroll
        for (int r = 0; r < 8; ++r) {
            int chunk = r * 64 + lane;
            int row = chunk >> 3, kcp = chunk & 7;
            int kcl = kcp ^ (row & 7);
            __builtin_amdgcn_global_load_lds(
                (gas_t)(const void*)(Bbase + (size_t)row * Q_BINS + kt + kcl * 8),
                (las_t)(void*)&Bsh[buf][chunk * 8], 16, 0, 0);
        }
    };

    f32x4 acc[4][4] = {};

    stage(0, 0);                            // 16 loads in flight
    int cur = 0;
    for (int t = 0; t < NT; ++t) {
        if (t + 1 < NT) {
            stage(cur ^ 1, t + 1);          // 16 newest loads (next tile)
            // wait for buf[cur]'s 16 (issued one full iteration ago);
            // next tile's 16 stay in flight across the compute phase.
            asm volatile("s_waitcnt vmcnt(16)" ::: "memory");
        } else {
            asm volatile("s_waitcnt vmcnt(0)" ::: "memory");
        }

        f16x8 a[4][2], b[4][2];
        #pragma unroll
        for (int m = 0; m < 4; ++m) {
            int row = m * 16 + fr;
            #pragma unroll
            for (int kk = 0; kk < 2; ++kk) {
                int kcp = (kk * 4 + fq) ^ (fr & 7);      // swizzled read
                a[m][kk] = *reinterpret_cast<const f16x8*>(
                    &Ash[cur][row * 64 + kcp * 8]);
            }
        }
        #pragma unroll
        for (int n = 0; n < 4; ++n) {
            int row = n * 16 + fr;
            #pragma unroll
            for (int kk = 0; kk < 2; ++kk) {
                int kcp = (kk * 4 + fq) ^ (fr & 7);
                b[n][kk] = *reinterpret_cast<const f16x8*>(
                    &Bsh[cur][row * 64 + kcp * 8]);
            }
        }

        __builtin_amdgcn_s_setprio(1);      // T5: favor the MFMA cluster
        #pragma unroll
        for (int kk = 0; kk < 2; ++kk)
            #pragma unroll
            for (int m = 0; m < 4; ++m)
                #pragma unroll
                for (int n = 0; n < 4; ++n)
                    acc[m][n] = __builtin_amdgcn_mfma_f32_16x16x32_f16(
                        a[m][kk], b[n][kk], acc[m][n], 0, 0, 0);
        __builtin_amdgcn_s_setprio(0);

        cur ^= 1;
    }

    // epilogue: C/D layout col = lane&15, row = (lane>>4)*4 + reg
    const int crow = fq * 4;
    #pragma unroll
    for (int m = 0; m < 4; ++m)
        #pragma unroll
        for (int n = 0; n < 4; ++n)
            #pragma unroll
            for (int r = 0; r < 4; ++r) {
                int grow = bx * 64 + m * 16 + crow + r;
                int gcol = by * 64 + n * 16 + fr;
                out[(size_t)grow * DMODEL + gcol] = acc[m][n][r];
            }
}

// ---------------------------------------------------------------- fallback
// (direct evaluation, used only if the workspace is too small)
__global__ __launch_bounds__(256)
void spatial_embed_fallback(const float* __restrict__ coords,
                            const unsigned char* __restrict__ mask,
                            float* __restrict__ out)
{
    const int bi  = blockIdx.x;
    const int b   = bi >> 11;
    const int i   = bi & (N_TOK - 1);
    const int tid = threadIdx.x;

    __shared__ float2 ra[N_TOK];
    const float xi = coords[(size_t)bi * 3 + 0];
    const float yi = coords[(size_t)bi * 3 + 1];
    const float zi = coords[(size_t)bi * 3 + 2];
    const unsigned char* mrow = mask + (size_t)b * N_TOK;

    for (int j = tid; j < N_TOK; j += 256) {
        const float* cj = coords + ((size_t)b * N_TOK + j) * 3;
        float dx = xi - cj[0], dy = yi - cj[1], dz = zi - cj[2];
        float sq = fmaf(dx, dx, fmaf(dy, dy, dz * dz));
        bool pv = (j != i) && (mrow[j] == 0);
        sq = pv ? sq : 1.0f;
        float inv_r = rsqrtf(sq);
        ra[j] = make_float2(sq * inv_r, pv ? inv_r * INV_FOUR_PI : 0.0f);
    }
    __syncthreads();

    const float inv_lam = 0.5f * exp2f(-(float)tid * LOG2_50_OVER_255);
    float re = 0.0f, im = 0.0f;
    #pragma unroll 8
    for (int j = 0; j < N_TOK; ++j) {
        float2 v = ra[j];
        float t  = v.x * inv_lam;
        t -= floorf(t);
        re = fmaf(v.y, __builtin_amdgcn_cosf(t), re);
        im = fmaf(v.y, __builtin_amdgcn_sinf(t), im);
    }
    const float vi = (mrow[i] == 0) ? 1.0f : 0.0f;
    reinterpret_cast<float2*>(out)[(size_t)bi * 256 + tid] =
        make_float2(re * vi, im * vi);
}

extern "C" void kernel_launch(void* const* d_in, const int* in_sizes, int n_in,
                              void* d_out, int out_size, void* d_ws, size_t ws_size,
                              hipStream_t stream)
{
    const float* coords       = (const float*)d_in[0];
    const unsigned char* mask = (const unsigned char*)d_in[1];
    float* out                = (float*)d_out;
    const int BN = in_sizes[1];                       // B * N = 8192

    const size_t W_BYTES = (size_t)8192 * Q_BINS * sizeof(_Float16);   // 12.6 MB
    const size_t T_BYTES = (size_t)DMODEL * Q_BINS * sizeof(_Float16); //  0.8 MB

    if (BN == 8192 && ws_size >= W_BYTES + T_BYTES) {
        _Float16* Wg = (_Float16*)d_ws;
        _Float16* Tg = (_Float16*)((char*)d_ws + W_BYTES);
        bin_table_kernel<<<8192 + DMODEL, 256, 0, stream>>>(coords, mask, Wg, Tg);
        gemm_kernel<<<1024, 64, 0, stream>>>(Wg, Tg, out);
    } else {
        spatial_embed_fallback<<<BN, 256, 0, stream>>>(coords, mask, out);
    }
}

// Round 13
// 37.731 us; speedup vs baseline: 1.6893x; 1.1776x over previous
//
#include <hip/hip_runtime.h>

// SpatialEmbedding via hybrid histogram + cos/sin table + f16 MFMA GEMM.
// out[bi][2m]   = sum_j amp_ij * cos(k_m r_ij)
// out[bi][2m+1] = sum_j amp_ij * sin(k_m r_ij),  amp = 1/(4*pi*r)
// Pipeline: fused bin+table kernel -> W[8192][512] f16, T[512][512] f16;
// then out = W * T^T via MFMA GEMM (wave-private, barrier-free).
// R13: Q_BINS 768 -> 512 (DELTA=0.1875 exact): gemm steps 12->8, W 8.4 MB.
// Calibrated by R12 (Delta 0.094->0.125 moved absmax 0.0625->0.0752):
// predicted absmax ~0.10-0.13, under the 0.199 threshold.
// bin kernel is at the hard ds-atomic floor (~1 lane-op/cy/CU x 17.1M).

constexpr int N_TOK   = 2048;
constexpr int DMODEL  = 512;
constexpr int Q_BINS  = 512;
constexpr float R_MAX     = 96.0f;              // max pair distance ~90 A
constexpr float DELTA     = R_MAX / Q_BINS;     // 0.1875 (exact)
constexpr float INV_DELTA = Q_BINS / R_MAX;     // 16/3
constexpr float RC_SQ     = 36.0f;              // lerp below r=6 A (~2% of pairs)
constexpr float FXP_SCALE     = 16777216.0f;    // 2^24
constexpr float FXP_INV_SCALE = 1.0f / FXP_SCALE;

#define LOG2_50_OVER_255 0.0221327692901077f
#define INV_FOUR_PI      0.07957747154594767f

typedef _Float16 f16x8 __attribute__((ext_vector_type(8)));
typedef _Float16 f16x4 __attribute__((ext_vector_type(4)));
typedef float    f32x4 __attribute__((ext_vector_type(4)));

typedef const __attribute__((address_space(1))) unsigned int* gas_t;
typedef __attribute__((address_space(3))) unsigned int* las_t;

// ---------------------------------------------------------------- kernel 1
// Fused bin + table. Blocks [0,8192): per-row histogram W[bi][q] = sum_j amp
// (hybrid deposit, u32 fixed-point ds_add_u32 — native RMW path, at the
// ~1 lane-op/cy/CU ds-atomic floor). Blocks [8192,8704): table
// T[c][q] = cis(2*pi*q*DELTA/lam_m), c = 2m + (0=cos,1=sin), [512][512] f16.
__global__ __launch_bounds__(256)
void bin_table_kernel(const float* __restrict__ coords,
                      const unsigned char* __restrict__ mask,
                      _Float16* __restrict__ Wg,
                      _Float16* __restrict__ Tg)
{
    const int tid = threadIdx.x;

    if (blockIdx.x >= 8192) {
        // ---- table role (128 threads x f16x4 = 512 bins)
        const int c = blockIdx.x - 8192;       // 0..511
        const int m = c >> 1;
        const float inv_lam = 0.5f * exp2f(-(float)m * LOG2_50_OVER_255);
        if (tid < 128) {
            const int q0 = tid * 4;
            f16x4 v;
            #pragma unroll
            for (int u = 0; u < 4; ++u) {
                float t = ((float)(q0 + u) * DELTA) * inv_lam;  // revolutions
                t -= floorf(t);
                float val = (c & 1) ? __builtin_amdgcn_sinf(t)
                                    : __builtin_amdgcn_cosf(t);
                v[u] = (_Float16)val;
            }
            *reinterpret_cast<f16x4*>(&Tg[(size_t)c * Q_BINS + q0]) = v;
        }
        return;
    }

    // ---- bin role
    const int bi = blockIdx.x;
    const int b  = bi >> 11;
    const int i  = bi & (N_TOK - 1);

    __shared__ unsigned int W[Q_BINS];     // 2 KB u32 fixed-point accumulation
    for (int q = tid; q < Q_BINS; q += 256) W[q] = 0u;
    __syncthreads();

    const unsigned char* mrow = mask + (size_t)b * N_TOK;
    const bool row_valid = (mrow[i] == 0);

    if (row_valid) {
        const float xi = coords[(size_t)bi * 3 + 0];
        const float yi = coords[(size_t)bi * 3 + 1];
        const float zi = coords[(size_t)bi * 3 + 2];
        #pragma unroll
        for (int jj = 0; jj < N_TOK / 256; ++jj) {
            const int j = tid + jj * 256;
            if (j == i || mrow[j] != 0) continue;
            const float* cj = coords + ((size_t)b * N_TOK + j) * 3;
            float dx = xi - cj[0];
            float dy = yi - cj[1];
            float dz = zi - cj[2];
            float sq = fmaf(dx, dx, fmaf(dy, dy, dz * dz));
            float inv_r = rsqrtf(sq);
            float r     = sq * inv_r;
            float amp   = inv_r * INV_FOUR_PI;
            float u     = r * INV_DELTA;
            if (sq < RC_SQ) {
                // close pair: linear interp (second-order error; amp ~ 1/r
                // makes close pairs dominate first-order error). u < 32.
                float qf = floorf(u);
                int   q  = (int)qf;
                float w  = u - qf;
                atomicAdd(&W[q],     (unsigned int)(amp * (1.0f - w) * FXP_SCALE));
                atomicAdd(&W[q + 1], (unsigned int)(amp * w * FXP_SCALE));
            } else {
                // far pair: nearest bin (amp <= 0.0133; calibrated excess
                // ~0.07 max over all outputs at DELTA=0.1875)
                int q = (int)(u + 0.5f);
                if (q > Q_BINS - 1) q = Q_BINS - 1; // safety clamp
                atomicAdd(&W[q], (unsigned int)(amp * FXP_SCALE));
            }
        }
    }
    __syncthreads();

    // export 512 bins: 128 threads x f16x4
    if (tid < 128) {
        _Float16* wrow = Wg + (size_t)bi * Q_BINS;
        const int q0 = tid * 4;
        f16x4 v;
        #pragma unroll
        for (int u = 0; u < 4; ++u)
            v[u] = (_Float16)((float)W[q0 + u] * FXP_INV_SCALE);
        *reinterpret_cast<f16x4*>(&wrow[q0]) = v;
    }
}

// ---------------------------------------------------------------- kernel 2
// C(8192x512 f32) = W(8192x512 f16) * T^T  (T stored as [512][512]).
// WAVE-PRIVATE: 1024 blocks x 64 threads; each wave owns one 64x64 output
// tile (acc 4x4 of 16x16x32) and a private double-buffered LDS set
// (A 8KB + B 8KB per buffer = 32 KB/block; 4 blocks/CU = 128 KB, exact fit).
// K-loop sync = per-wave counted vmcnt(16) only; NO barriers. LDS staging is
// the coalescing reshaper: gload_lds reads 8x128B segments/instr vs the
// direct-gather's 16x64B (R10 regression).
// XOR-swizzle both sides (rule #21): phys 16B-chunk kcp at (row,kcp) holds
// logical kc = kcp^(row&7); source pre-swizzled, ds_read applies same XOR.
__global__ __launch_bounds__(64)
void gemm_kernel(const _Float16* __restrict__ Wg,
                 const _Float16* __restrict__ Tg,
                 float* __restrict__ out)
{
    constexpr int NT = Q_BINS / 64;         // 8 K-steps
    __shared__ _Float16 Ash[2][64 * 64];    // 8 KB per buffer
    __shared__ _Float16 Bsh[2][64 * 64];    // 32 KB total per block

    const int bid  = blockIdx.x;
    const int bx   = bid & 127;             // M-tile 0..127 (A-sharers co-XCD:
    const int by   = bid >> 7;              //   bids differ by 128 = 0 mod 8)
    const int lane = threadIdx.x;           // one wave

    const int fr = lane & 15;               // fragment row/col
    const int fq = lane >> 4;               // k-quad 0..3 (8 f16 each)

    const _Float16* Abase = Wg + (size_t)bx * 64 * Q_BINS;
    const _Float16* Bbase = Tg + (size_t)by * 64 * Q_BINS;

    // stage one 64x64 f16 tile pair: 512+512 16B chunks, 8+8 per lane.
    auto stage = [&](int buf, int t) {
        const int kt = t * 64;
        #pragma unroll
        for (int r = 0; r < 8; ++r) {
            int chunk = r * 64 + lane;
            int row = chunk >> 3, kcp = chunk & 7;
            int kcl = kcp ^ (row & 7);      // pre-swizzled source chunk
            __builtin_amdgcn_global_load_lds(
                (gas_t)(const void*)(Abase + (size_t)row * Q_BINS + kt + kcl * 8),
                (las_t)(void*)&Ash[buf][chunk * 8], 16, 0, 0);
        }
        #pragma unroll
        for (int r = 0; r < 8; ++r) {
            int chunk = r * 64 + lane;
            int row = chunk >> 3, kcp = chunk & 7;
            int kcl = kcp ^ (row & 7);
            __builtin_amdgcn_global_load_lds(
                (gas_t)(const void*)(Bbase + (size_t)row * Q_BINS + kt + kcl * 8),
                (las_t)(void*)&Bsh[buf][chunk * 8], 16, 0, 0);
        }
    };

    f32x4 acc[4][4] = {};

    stage(0, 0);                            // 16 loads in flight
    int cur = 0;
    for (int t = 0; t < NT; ++t) {
        if (t + 1 < NT) {
            stage(cur ^ 1, t + 1);          // 16 newest loads (next tile)
            // wait for buf[cur]'s 16 (issued one full iteration ago);
            // next tile's 16 stay in flight across the compute phase.
            asm volatile("s_waitcnt vmcnt(16)" ::: "memory");
        } else {
            asm volatile("s_waitcnt vmcnt(0)" ::: "memory");
        }

        f16x8 a[4][2], b[4][2];
        #pragma unroll
        for (int m = 0; m < 4; ++m) {
            int row = m * 16 + fr;
            #pragma unroll
            for (int kk = 0; kk < 2; ++kk) {
                int kcp = (kk * 4 + fq) ^ (fr & 7);      // swizzled read
                a[m][kk] = *reinterpret_cast<const f16x8*>(
                    &Ash[cur][row * 64 + kcp * 8]);
            }
        }
        #pragma unroll
        for (int n = 0; n < 4; ++n) {
            int row = n * 16 + fr;
            #pragma unroll
            for (int kk = 0; kk < 2; ++kk) {
                int kcp = (kk * 4 + fq) ^ (fr & 7);
                b[n][kk] = *reinterpret_cast<const f16x8*>(
                    &Bsh[cur][row * 64 + kcp * 8]);
            }
        }

        __builtin_amdgcn_s_setprio(1);      // T5: favor the MFMA cluster
        #pragma unroll
        for (int kk = 0; kk < 2; ++kk)
            #pragma unroll
            for (int m = 0; m < 4; ++m)
                #pragma unroll
                for (int n = 0; n < 4; ++n)
                    acc[m][n] = __builtin_amdgcn_mfma_f32_16x16x32_f16(
                        a[m][kk], b[n][kk], acc[m][n], 0, 0, 0);
        __builtin_amdgcn_s_setprio(0);

        cur ^= 1;
    }

    // epilogue: C/D layout col = lane&15, row = (lane>>4)*4 + reg
    const int crow = fq * 4;
    #pragma unroll
    for (int m = 0; m < 4; ++m)
        #pragma unroll
        for (int n = 0; n < 4; ++n)
            #pragma unroll
            for (int r = 0; r < 4; ++r) {
                int grow = bx * 64 + m * 16 + crow + r;
                int gcol = by * 64 + n * 16 + fr;
                out[(size_t)grow * DMODEL + gcol] = acc[m][n][r];
            }
}

// ---------------------------------------------------------------- fallback
// (direct evaluation, used only if the workspace is too small)
__global__ __launch_bounds__(256)
void spatial_embed_fallback(const float* __restrict__ coords,
                            const unsigned char* __restrict__ mask,
                            float* __restrict__ out)
{
    const int bi  = blockIdx.x;
    const int b   = bi >> 11;
    const int i   = bi & (N_TOK - 1);
    const int tid = threadIdx.x;

    __shared__ float2 ra[N_TOK];
    const float xi = coords[(size_t)bi * 3 + 0];
    const float yi = coords[(size_t)bi * 3 + 1];
    const float zi = coords[(size_t)bi * 3 + 2];
    const unsigned char* mrow = mask + (size_t)b * N_TOK;

    for (int j = tid; j < N_TOK; j += 256) {
        const float* cj = coords + ((size_t)b * N_TOK + j) * 3;
        float dx = xi - cj[0], dy = yi - cj[1], dz = zi - cj[2];
        float sq = fmaf(dx, dx, fmaf(dy, dy, dz * dz));
        bool pv = (j != i) && (mrow[j] == 0);
        sq = pv ? sq : 1.0f;
        float inv_r = rsqrtf(sq);
        ra[j] = make_float2(sq * inv_r, pv ? inv_r * INV_FOUR_PI : 0.0f);
    }
    __syncthreads();

    const float inv_lam = 0.5f * exp2f(-(float)tid * LOG2_50_OVER_255);
    float re = 0.0f, im = 0.0f;
    #pragma unroll 8
    for (int j = 0; j < N_TOK; ++j) {
        float2 v = ra[j];
        float t  = v.x * inv_lam;
        t -= floorf(t);
        re = fmaf(v.y, __builtin_amdgcn_cosf(t), re);
        im = fmaf(v.y, __builtin_amdgcn_sinf(t), im);
    }
    const float vi = (mrow[i] == 0) ? 1.0f : 0.0f;
    reinterpret_cast<float2*>(out)[(size_t)bi * 256 + tid] =
        make_float2(re * vi, im * vi);
}

extern "C" void kernel_launch(void* const* d_in, const int* in_sizes, int n_in,
                              void* d_out, int out_size, void* d_ws, size_t ws_size,
                              hipStream_t stream)
{
    const float* coords       = (const float*)d_in[0];
    const unsigned char* mask = (const unsigned char*)d_in[1];
    float* out                = (float*)d_out;
    const int BN = in_sizes[1];                       // B * N = 8192

    const size_t W_BYTES = (size_t)8192 * Q_BINS * sizeof(_Float16);   // 8.4 MB
    const size_t T_BYTES = (size_t)DMODEL * Q_BINS * sizeof(_Float16); // 0.5 MB

    if (BN == 8192 && ws_size >= W_BYTES + T_BYTES) {
        _Float16* Wg = (_Float16*)d_ws;
        _Float16* Tg = (_Float16*)((char*)d_ws + W_BYTES);
        bin_table_kernel<<<8192 + DMODEL, 256, 0, stream>>>(coords, mask, Wg, Tg);
        gemm_kernel<<<1024, 64, 0, stream>>>(Wg, Tg, out);
    } else {
        spatial_embed_fallback<<<BN, 256, 0, stream>>>(coords, mask, out);
    }
}